// Round 10
// baseline (253.246 us; speedup 1.0000x reference)
//
#include <hip/hip_runtime.h>
#include <math.h>

#define N_NODES 50000
#define N_EDGES 400000
#define R_REL   35
#define B_BASES 12
#define C_DIM   128
#define HL_DIM  38
#define RI2     70
#define NP      50304         // padded permuted node space (mult of 64)
#define NB_HIST 196           // ceil(50000/256)
#define NBUCK   786           // NP/64 — one bucket per k_node tile
#define EPB     2048          // edges per scatter block (196*2048 >= 400000)
#define CAP     704           // fixed bucket segment capacity (mean 512, 8.5 sigma)

// ---- ws float offsets ----
#define OFF_WT     0          // w[ri][c] = [70][128] = 8960
#define OFF_WQ     8960       // [70]
#define OFF_WK     9030       // [70]
#define OFF_LE     9100       // [2]
#define OFF_META   9104       // 16 ints: counts[4]@0, base_pad[4]@4
#define OFF_HBLK   9120       // int[196][4]
#define OFF_BBASE  9904       // int[196][4]
#define OFF_PERM   10688      // int[50000]
#define OFF_INV    60688      // int[NP]
#define OFF_ECUR   110992     // int[786] global bucket cursors
#define OFF_EREC   111780     // float4[786*704]  (111780 % 4 == 0 -> 16B aligned)

// ---- k_node LDS float offsets (aggressive region aliasing, 39.06 KB total) ----
// phase0/GEMM1 : CH [0,3584) double-buffered wT chunks ; ST [3584,8344) sT[70][68]
// after GEMM1  : H  [0,8192)  H[128][64]   (CH+ST dead)
// GEMM2        : W0Q [8344,9624) quarter chunk [32][40]
// after GEMM2  : Y0T [0,3264) ; W1S [3264,4784) ; W2S [4784,6304) ; Y1T [6304,9568)
// after GEMM4  : Y2T [0,3264)
#define CH    0
#define ST    3584
#define HH    0
#define Y0T   0
#define W1S   3264
#define W2S   4784
#define Y1T   6304
#define Y2T   0
#define W0Q   8344
#define SM_DINV 9624   // [64]
#define SM_FW   9688   // [76]
#define SM_FB   9764   // [2]
#define LDS_FLOATS 9766

// K1: wT init + node-type histogram + cursor zero
__global__ __launch_bounds__(256) void k_init(const int* __restrict__ node_type,
                                              const float* __restrict__ basis,
                                              const float* __restrict__ att_rel,
                                              float* __restrict__ ws) {
    int b = blockIdx.x, tid = threadIdx.x;
    if (b < NB_HIST) {
        __shared__ int lh[4];
        if (tid < 4) lh[tid] = 0;
        __syncthreads();
        int i = b * 256 + tid;
        if (i < N_NODES) atomicAdd(&lh[node_type[i]], 1);
        __syncthreads();
        if (tid < 4) ((int*)(ws + OFF_HBLK))[b * 4 + tid] = lh[tid];
    } else if (b < NB_HIST + 35) {
        int idx = (b - NB_HIST) * 256 + tid;
        if (idx < RI2 * C_DIM) {
            int c  = idx & (C_DIM - 1);
            int ri = idx >> 7;
            int r = ri >> 1, ii = ri & 1;
            float acc = 0.f;
            #pragma unroll
            for (int bb = 0; bb < B_BASES; ++bb)
                acc += att_rel[r * B_BASES + bb] * basis[(bb * 2 + ii) * C_DIM + c];
            ws[OFF_WT + idx] = acc;
        }
    } else {
        for (int i = tid; i < NBUCK; i += 256) ((int*)(ws + OFF_ECUR))[i] = 0;
    }
}

// K2: node scan (block 0) + wq/wk/le projections (blocks 1..18)
__global__ __launch_bounds__(256) void k_scanproj(const float* __restrict__ q_att,
                                                  const float* __restrict__ k_att,
                                                  const float* __restrict__ e_att,
                                                  const float* __restrict__ lin_edge_W,
                                                  float* __restrict__ ws) {
    int b = blockIdx.x, tid = threadIdx.x;
    int lane = tid & 63, wv = tid >> 6;
    if (b == 0) {
        __shared__ int lh[NB_HIST * 4];
        __shared__ int basel[4];
        const int* hblk = (const int*)(ws + OFF_HBLK);
        for (int i = tid; i < NB_HIST * 4; i += 256) lh[i] = hblk[i];
        __syncthreads();
        __shared__ int tot[4];
        if (tid < 4) {
            int run = 0;
            for (int bb = 0; bb < NB_HIST; ++bb) {
                int v = lh[bb * 4 + tid];
                lh[bb * 4 + tid] = run;
                run += v;
            }
            tot[tid] = run;
        }
        __syncthreads();
        if (tid == 0) {
            int* meta = (int*)(ws + OFF_META);
            int t0 = tot[0], t1 = tot[1], t2 = tot[2], t3 = tot[3];
            int b1 = ((t0 + 63) >> 6) << 6;
            int b2 = b1 + (((t1 + 63) >> 6) << 6);
            int b3 = b2 + (((t2 + 63) >> 6) << 6);
            meta[0] = t0; meta[1] = t1; meta[2] = t2; meta[3] = t3;
            meta[4] = 0;  meta[5] = b1; meta[6] = b2; meta[7] = b3;
            basel[0] = 0; basel[1] = b1; basel[2] = b2; basel[3] = b3;
        }
        __syncthreads();
        for (int i = tid; i < NB_HIST * 4; i += 256)
            ((int*)(ws + OFF_BBASE))[i] = basel[i & 3] + lh[i];
    } else {
        int u = (b - 1) * 4 + wv;    // [0, 72)
        if (u < RI2) {
            const float* wr = ws + OFF_WT + u * C_DIM;
            float w1 = wr[lane], w2 = wr[64 + lane];
            float aq = w1 * q_att[lane] + w2 * q_att[64 + lane];
            float ak = w1 * k_att[lane] + w2 * k_att[64 + lane];
            #pragma unroll
            for (int off = 32; off; off >>= 1) {
                aq += __shfl_xor(aq, off, 64);
                ak += __shfl_xor(ak, off, 64);
            }
            if (lane == 0) { ws[OFF_WQ + u] = aq; ws[OFF_WK + u] = ak; }
        } else if (u < 72) {
            int j = u - RI2;
            const float* er = lin_edge_W + j * C_DIM;
            float a = er[lane] * e_att[lane] + er[64 + lane] * e_att[64 + lane];
            #pragma unroll
            for (int off = 32; off; off >>= 1) a += __shfl_xor(a, off, 64);
            if (lane == 0) ws[OFF_LE + j] = a;
        }
    }
}

// K3: node permutation — ballots + LDS partials, atomic-free, deterministic
__global__ __launch_bounds__(256) void k_perm(const int* __restrict__ node_type,
                                              float* __restrict__ ws) {
    __shared__ int wcnt[4][4];
    int tid = threadIdx.x;
    int lane = tid & 63, wv = tid >> 6;
    int n = blockIdx.x * 256 + tid;
    bool active = n < N_NODES;
    int ty = active ? node_type[n] : -1;
    int myrank = 0;
    #pragma unroll
    for (int t = 0; t < 4; ++t) {
        unsigned long long m = __ballot(ty == t);
        if (lane == 0) wcnt[wv][t] = __popcll(m);
        if (ty == t) myrank = __popcll(m & ((1ULL << lane) - 1ULL));
    }
    __syncthreads();
    if (active) {
        int pre = 0;
        for (int w2 = 0; w2 < wv; ++w2) pre += wcnt[w2][ty];
        int p = ((const int*)(ws + OFF_BBASE))[blockIdx.x * 4 + ty] + pre + myrank;
        ((int*)(ws + OFF_PERM))[n] = p;
        ((int*)(ws + OFF_INV))[p] = n;
    }
}

// K4: single-pass bucketed scatter — LDS hist, chunk reservation, record stores
__global__ __launch_bounds__(256) void k_escatter(const float* __restrict__ x,
                                                  const int* __restrict__ edge_index,
                                                  const int* __restrict__ edge_type,
                                                  const float* __restrict__ edge_attr,
                                                  float* __restrict__ ws) {
    __shared__ int hist[NBUCK];
    __shared__ int sbase[NBUCK];
    __shared__ float swq[RI2], swk[RI2], sle[2];
    int tid = threadIdx.x;
    for (int i = tid; i < NBUCK; i += 256) hist[i] = 0;
    if (tid < RI2) { swq[tid] = ws[OFF_WQ + tid]; swk[tid] = ws[OFF_WK + tid]; }
    if (tid < 2) sle[tid] = ws[OFF_LE + tid];
    __syncthreads();

    const int* perm = (const int*)(ws + OFF_PERM);
    int base = blockIdx.x * EPB;
    int   rb[8], rm[8];
    float rex[8], rsx[8], rsy[8];
    #pragma unroll
    for (int k = 0; k < 8; ++k) {
        int e = base + k * 256 + tid;
        rb[k] = -1;
        if (e < N_EDGES) {
            int src = edge_index[e];
            int dst = edge_index[N_EDGES + e];
            int r   = edge_type[e];
            int p   = perm[dst];
            float2 ea = *(const float2*)(edge_attr + 2 * e);
            float2 xs = *(const float2*)(x + 2 * src);
            float2 xd = *(const float2*)(x + 2 * dst);
            float alpha = xd.x * swq[2 * r] + xd.y * swq[2 * r + 1]
                        + xs.x * swk[2 * r] + xs.y * swk[2 * r + 1]
                        + ea.x * sle[0]     + ea.y * sle[1];
            alpha = alpha > 0.f ? alpha : 0.2f * alpha;
            float ex = __expf(alpha);
            rb[k]  = p >> 6;
            rm[k]  = (r << 6) | (p & 63);
            rex[k] = ex;
            rsx[k] = ex * xs.x;
            rsy[k] = ex * xs.y;
            atomicAdd(&hist[rb[k]], 1);
        }
    }
    __syncthreads();
    int* gcur = (int*)(ws + OFF_ECUR);
    for (int i = tid; i < NBUCK; i += 256) {
        int c = hist[i];
        sbase[i] = (c > 0) ? atomicAdd(&gcur[i], c) : 0;
    }
    __syncthreads();
    float4* rec = (float4*)(ws + OFF_EREC);
    #pragma unroll
    for (int k = 0; k < 8; ++k) {
        if (rb[k] >= 0) {
            int slot = atomicAdd(&sbase[rb[k]], 1);
            rec[(size_t)rb[k] * CAP + slot] =
                make_float4(__int_as_float(rm[k]), rex[k], rsx[k], rsy[k]);
        }
    }
}

// K5: fused node pass v2 — 39 KB LDS (4 blocks/CU), wave3 idles in MLP phases
__global__ __launch_bounds__(256, 4) void k_node(
        const float* __restrict__ ws, const float* __restrict__ conv_bias,
        const float* __restrict__ lin0_W, const float* __restrict__ lin0_b,
        const float* __restrict__ lin1_W, const float* __restrict__ lin1_b,
        const float* __restrict__ lin2_W, const float* __restrict__ lin2_b,
        const float* __restrict__ fin_W,  const float* __restrict__ fin_b,
        float* __restrict__ out) {
    __shared__ float L[LDS_FLOATS];
    int tid  = threadIdx.x;
    int lane = tid & 63;
    int wv   = tid >> 6;
    int p0   = blockIdx.x * 64;

    const int* meta = (const int*)(ws + OFF_META);
    int b1 = meta[5], b2 = meta[6], b3 = meta[7];
    int t  = (p0 >= b1) + (p0 >= b2) + (p0 >= b3);   // block-uniform
    int bp = meta[4 + t];
    int cnt = meta[t];

    // ---------- phase 0: zero sT + den, stage FW/FB, wT chunk 0
    for (int i = tid; i < RI2 * 68; i += 256) L[ST + i] = 0.f;
    if (tid < 64) L[SM_DINV + tid] = 0.f;
    if (tid >= 64 && tid < 142) {
        int i = tid - 64;
        if (i < 76) L[SM_FW + i] = fin_W[t * 76 + i];
        else        L[SM_FB + i - 76] = fin_b[t * 2 + i - 76];
    }
    const float* wT_g = ws + OFF_WT;
    for (int i4 = tid; i4 < 448; i4 += 256) {
        float4 v = ((const float4*)wT_g)[i4];
        *(float4*)&L[CH + i4 * 4] = v;
    }
    __syncthreads();

    // ---------- phase 1: accumulate this bucket's edge records (LDS atomics)
    {
        int ecnt = ((const int*)(ws + OFF_ECUR))[blockIdx.x];
        const float4* rec = (const float4*)(ws + OFF_EREC) + (size_t)blockIdx.x * CAP;
        for (int i = tid; i < ecnt; i += 256) {
            float4 v = rec[i];
            int m = __float_as_int(v.x);
            int n = m & 63, r = m >> 6;
            atomicAdd(&L[ST + (2 * r) * 68 + n],     v.z);
            atomicAdd(&L[ST + (2 * r + 1) * 68 + n], v.w);
            atomicAdd(&L[SM_DINV + n],               v.y);
        }
    }
    __syncthreads();
    if (tid < 64) L[SM_DINV + tid] = 1.0f / (L[SM_DINV + tid] + 1e-16f);

    // ---------- GEMM1: H[64n x 128c] = sT x wT ; wave c-slice 32, lane 4n x 8c
    int ng = lane & 15, cg_ = lane >> 4;
    int c0 = wv * 32 + cg_ * 8;
    float acc[32];
    #pragma unroll
    for (int i = 0; i < 32; ++i) acc[i] = 0.f;
    int cur = 0;
    for (int q = 0; q < 5; ++q) {
        float4 pf0, pf1;
        if (q < 4) {
            const float4* src = (const float4*)(wT_g + (q + 1) * 1792);
            pf0 = src[tid];
            if (tid < 192) pf1 = src[tid + 256];
        }
        const float* wb = &L[CH + cur * 1792];
        #pragma unroll
        for (int kk = 0; kk < 14; ++kk) {
            float4 a4 = *(const float4*)&L[ST + (q * 14 + kk) * 68 + ng * 4];
            float4 wa = *(const float4*)&wb[kk * 128 + c0];
            float4 wc = *(const float4*)&wb[kk * 128 + c0 + 4];
            float a_[4] = {a4.x, a4.y, a4.z, a4.w};
            float w_[8] = {wa.x, wa.y, wa.z, wa.w, wc.x, wc.y, wc.z, wc.w};
            #pragma unroll
            for (int ni = 0; ni < 4; ++ni)
                #pragma unroll
                for (int ci = 0; ci < 8; ++ci)
                    acc[ni * 8 + ci] += a_[ni] * w_[ci];
        }
        if (q < 4) {
            float* dstb = &L[CH + (cur ^ 1) * 1792];
            *(float4*)&dstb[tid * 4] = pf0;
            if (tid < 192) *(float4*)&dstb[(tid + 256) * 4] = pf1;
        }
        cur ^= 1;
        __syncthreads();
    }
    // all waves past final barrier: CH + ST dead -> H may overwrite [0,8192)

    // epilogue 1: h = relu(acc*dinv + cb) -> H[c][n]  (conv_bias from global)
    {
        float4 dv = *(const float4*)&L[SM_DINV + ng * 4];
        float d_[4] = {dv.x, dv.y, dv.z, dv.w};
        #pragma unroll
        for (int ci = 0; ci < 8; ++ci) {
            float cb = conv_bias[c0 + ci];
            float4 hv;
            float h0 = acc[0 * 8 + ci] * d_[0] + cb;
            float h1 = acc[1 * 8 + ci] * d_[1] + cb;
            float h2 = acc[2 * 8 + ci] * d_[2] + cb;
            float h3 = acc[3 * 8 + ci] * d_[3] + cb;
            hv.x = h0 > 0.f ? h0 : 0.f;
            hv.y = h1 > 0.f ? h1 : 0.f;
            hv.z = h2 > 0.f ? h2 : 0.f;
            hv.w = h3 > 0.f ? h3 : 0.f;
            *(float4*)&L[HH + (c0 + ci) * 64 + ng * 4] = hv;
        }
    }
    __syncthreads();   // H complete

    // ---------- GEMM2: y0[64n x 48j] = H x W0 ; waves 0..2 (j covered by 48), wave 3 idles
    const float* W0g = lin0_W + t * C_DIM * HL_DIM;
    int jg = lane >> 4;
    int j0 = wv * 16 + jg * 4;
    float acc2[16];
    #pragma unroll
    for (int i = 0; i < 16; ++i) acc2[i] = 0.f;
    for (int q = 0; q < 4; ++q) {
        // stage W0 quarter chunk q: rows [q*32, q*32+32) -> [32][40]
        for (int i = tid; i < 1216; i += 256) {
            int cc = i / 38, j = i - cc * 38;
            L[W0Q + cc * 40 + j] = W0g[q * 1216 + i];
        }
        __syncthreads();
        if (wv < 3) {
            #pragma unroll 4
            for (int kk = 0; kk < 32; ++kk) {
                int c = q * 32 + kk;
                float4 a4 = *(const float4*)&L[HH + c * 64 + ng * 4];
                float4 w4 = *(const float4*)&L[W0Q + kk * 40 + j0];
                float a_[4] = {a4.x, a4.y, a4.z, a4.w};
                float w_[4] = {w4.x, w4.y, w4.z, w4.w};
                #pragma unroll
                for (int ni = 0; ni < 4; ++ni)
                    #pragma unroll
                    for (int ji = 0; ji < 4; ++ji)
                        acc2[ni * 4 + ji] += a_[ni] * w_[ji];
            }
        }
        __syncthreads();
    }
    // epilogue 2 (waves 0..2): relu(y0 + b0) -> y0T[j][n] over dead H
    if (wv < 3) {
        #pragma unroll
        for (int ji = 0; ji < 4; ++ji) {
            int j = j0 + ji;
            float b = (j < HL_DIM) ? lin0_b[t * HL_DIM + j] : 0.f;
            float4 yv;
            float y0 = acc2[0 * 4 + ji] + b;
            float y1 = acc2[1 * 4 + ji] + b;
            float y2 = acc2[2 * 4 + ji] + b;
            float y3 = acc2[3 * 4 + ji] + b;
            yv.x = y0 > 0.f ? y0 : 0.f;
            yv.y = y1 > 0.f ? y1 : 0.f;
            yv.z = y2 > 0.f ? y2 : 0.f;
            yv.w = y3 > 0.f ? y3 : 0.f;
            *(float4*)&L[Y0T + j * 68 + ng * 4] = yv;
        }
    }
    // stage W1/W2 into dead H region (disjoint from Y0T)
    {
        const float* W1g = lin1_W + t * HL_DIM * HL_DIM;
        const float* W2g = lin2_W + t * HL_DIM * HL_DIM;
        for (int i = tid; i < 1444; i += 256) {
            int cc = i / 38, j = i - cc * 38;
            L[W1S + cc * 40 + j] = W1g[i];
            L[W2S + cc * 40 + j] = W2g[i];
        }
    }
    __syncthreads();

    // ---------- GEMM3: y1 = y0 x W1 (k=38, resident) ; waves 0..2
    float acc3[16];
    #pragma unroll
    for (int i = 0; i < 16; ++i) acc3[i] = 0.f;
    if (wv < 3) {
        #pragma unroll 2
        for (int kk = 0; kk < HL_DIM; ++kk) {
            float4 a4 = *(const float4*)&L[Y0T + kk * 68 + ng * 4];
            float4 w4 = *(const float4*)&L[W1S + kk * 40 + j0];
            float a_[4] = {a4.x, a4.y, a4.z, a4.w};
            float w_[4] = {w4.x, w4.y, w4.z, w4.w};
            #pragma unroll
            for (int ni = 0; ni < 4; ++ni)
                #pragma unroll
                for (int ji = 0; ji < 4; ++ji)
                    acc3[ni * 4 + ji] += a_[ni] * w_[ji];
        }
        // y1T region disjoint from Y0T/W1S/W2S -> no barrier needed before write
        #pragma unroll
        for (int ji = 0; ji < 4; ++ji) {
            int j = j0 + ji;
            float b = (j < HL_DIM) ? lin1_b[t * HL_DIM + j] : 0.f;
            float4 yv;
            float y0 = acc3[0 * 4 + ji] + b;
            float y1 = acc3[1 * 4 + ji] + b;
            float y2 = acc3[2 * 4 + ji] + b;
            float y3 = acc3[3 * 4 + ji] + b;
            yv.x = y0 > 0.f ? y0 : 0.f;
            yv.y = y1 > 0.f ? y1 : 0.f;
            yv.z = y2 > 0.f ? y2 : 0.f;
            yv.w = y3 > 0.f ? y3 : 0.f;
            *(float4*)&L[Y1T + j * 68 + ng * 4] = yv;
        }
    }
    __syncthreads();

    // ---------- GEMM4: y2 = y1 x W2 (no relu) ; waves 0..2 ; y2T over dead Y0T
    if (wv < 3) {
        float acc4[16];
        #pragma unroll
        for (int i = 0; i < 16; ++i) acc4[i] = 0.f;
        #pragma unroll 2
        for (int kk = 0; kk < HL_DIM; ++kk) {
            float4 a4 = *(const float4*)&L[Y1T + kk * 68 + ng * 4];
            float4 w4 = *(const float4*)&L[W2S + kk * 40 + j0];
            float a_[4] = {a4.x, a4.y, a4.z, a4.w};
            float w_[4] = {w4.x, w4.y, w4.z, w4.w};
            #pragma unroll
            for (int ni = 0; ni < 4; ++ni)
                #pragma unroll
                for (int ji = 0; ji < 4; ++ji)
                    acc4[ni * 4 + ji] += a_[ni] * w_[ji];
        }
        #pragma unroll
        for (int ji = 0; ji < 4; ++ji) {
            int j = j0 + ji;
            float b = (j < HL_DIM) ? lin2_b[t * HL_DIM + j] : 0.f;
            float4 yv;
            yv.x = acc4[0 * 4 + ji] + b;
            yv.y = acc4[1 * 4 + ji] + b;
            yv.z = acc4[2 * 4 + ji] + b;
            yv.w = acc4[3 * 4 + ji] + b;
            *(float4*)&L[Y2T + j * 68 + ng * 4] = yv;
        }
    }
    __syncthreads();

    // ---------- final: fin [38]->[2], thread-per-node (wave 0)
    if (tid < 64) {
        int p = p0 + tid;
        bool valid = (p - bp) < cnt;
        float o0 = L[SM_FB], o1 = L[SM_FB + 1];
        for (int jj = 0; jj < HL_DIM; ++jj) {
            float v = L[Y2T + jj * 68 + tid];
            float2 f = *(const float2*)&L[SM_FW + jj * 2];
            o0 += v * f.x;
            o1 += v * f.y;
        }
        if (t == 0) o1 = fabsf(o1);
        if (valid) {
            int orig = ((const int*)(ws + OFF_INV))[p];
            ((float2*)out)[orig] = make_float2(o0, o1);
        }
    }
}

extern "C" void kernel_launch(void* const* d_in, const int* in_sizes, int n_in,
                              void* d_out, int out_size, void* d_ws, size_t ws_size,
                              hipStream_t stream) {
    const float* x          = (const float*)d_in[0];
    const int*   edge_index = (const int*)  d_in[1];
    const int*   edge_type  = (const int*)  d_in[2];
    const float* edge_attr  = (const float*)d_in[3];
    const int*   node_type  = (const int*)  d_in[4];
    const float* basis      = (const float*)d_in[5];
    const float* att_rel    = (const float*)d_in[6];
    const float* q_att      = (const float*)d_in[7];
    const float* k_att      = (const float*)d_in[8];
    const float* e_att      = (const float*)d_in[9];
    const float* lin_edge_W = (const float*)d_in[10];
    const float* conv_bias  = (const float*)d_in[11];
    const float* lin0_W     = (const float*)d_in[12];
    const float* lin0_b     = (const float*)d_in[13];
    const float* lin1_W     = (const float*)d_in[14];
    const float* lin1_b     = (const float*)d_in[15];
    const float* lin2_W     = (const float*)d_in[16];
    const float* lin2_b     = (const float*)d_in[17];
    const float* fin_W      = (const float*)d_in[18];
    const float* fin_b      = (const float*)d_in[19];

    float* ws  = (float*)d_ws;
    float* out = (float*)d_out;

    k_init    <<<NB_HIST + 35 + 1, 256, 0, stream>>>(node_type, basis, att_rel, ws);
    k_scanproj<<<19, 256, 0, stream>>>(q_att, k_att, e_att, lin_edge_W, ws);
    k_perm    <<<NB_HIST, 256, 0, stream>>>(node_type, ws);
    k_escatter<<<NB_HIST, 256, 0, stream>>>(x, edge_index, edge_type, edge_attr, ws);
    k_node    <<<NBUCK, 256, 0, stream>>>(ws, conv_bias,
                                          lin0_W, lin0_b, lin1_W, lin1_b,
                                          lin2_W, lin2_b, fin_W, fin_b, out);
}

// Round 11
// 177.714 us; speedup vs baseline: 1.4250x; 1.4250x over previous
//
#include <hip/hip_runtime.h>
#include <math.h>

#define N_NODES 50000
#define N_EDGES 400000
#define R_REL   35
#define B_BASES 12
#define C_DIM   128
#define HL_DIM  38
#define RI2     70
#define NP      50304         // padded permuted node space (mult of 64)
#define NB_HIST 196           // ceil(50000/256)
#define NBUCK   786           // NP/64 — one bucket per k_node tile
#define EPB     2048          // edges per scatter block (196*2048 >= 400000)
#define CAP     704           // fixed bucket segment capacity (mean 512, 8.5 sigma)

// ---- ws float offsets ----
#define OFF_WT     0          // w[ri][c] = [70][128] = 8960
#define OFF_WQ     8960       // [70]
#define OFF_WK     9030       // [70]
#define OFF_LE     9100       // [2]
#define OFF_META   9104       // 16 ints: counts[4]@0, base_pad[4]@4
#define OFF_HBLK   9120       // int[196][4]
#define OFF_BBASE  9904       // int[196][4]
#define OFF_PERM   10688      // int[50000]
#define OFF_INV    60688      // int[NP]
#define OFF_ECUR   110992     // int[786] global bucket cursors
#define OFF_EREC   111780     // float4[786*704]  (111780 % 4 == 0 -> 16B aligned)

// ---- k_node LDS float offsets (region aliasing, 39.06 KB total) ----
// phase0/GEMM1 : CH [0,3584) double-buffered wT chunks ; ST [3584,8344) sT[70][68]
// after GEMM1  : H  [0,8192)  H[128][64]   (CH+ST dead)
// GEMM2        : W0Q [8344,9624) quarter chunk [32][40]
// after GEMM2  : Y0T [0,3264) ; W1S [3264,4784) ; W2S [4784,6304) ; Y1T [6304,9568)
// after GEMM4  : Y2T [0,3264)
#define CH    0
#define ST    3584
#define HH    0
#define Y0T   0
#define W1S   3264
#define W2S   4784
#define Y1T   6304
#define Y2T   0
#define W0Q   8344
#define SM_DINV 9624   // [64]
#define SM_FW   9688   // [76]
#define SM_FB   9764   // [2]
#define LDS_FLOATS 9766

// K1: wT init + node-type histogram + cursor zero
__global__ __launch_bounds__(256) void k_init(const int* __restrict__ node_type,
                                              const float* __restrict__ basis,
                                              const float* __restrict__ att_rel,
                                              float* __restrict__ ws) {
    int b = blockIdx.x, tid = threadIdx.x;
    if (b < NB_HIST) {
        __shared__ int lh[4];
        if (tid < 4) lh[tid] = 0;
        __syncthreads();
        int i = b * 256 + tid;
        if (i < N_NODES) atomicAdd(&lh[node_type[i]], 1);
        __syncthreads();
        if (tid < 4) ((int*)(ws + OFF_HBLK))[b * 4 + tid] = lh[tid];
    } else if (b < NB_HIST + 35) {
        int idx = (b - NB_HIST) * 256 + tid;
        if (idx < RI2 * C_DIM) {
            int c  = idx & (C_DIM - 1);
            int ri = idx >> 7;
            int r = ri >> 1, ii = ri & 1;
            float acc = 0.f;
            #pragma unroll
            for (int bb = 0; bb < B_BASES; ++bb)
                acc += att_rel[r * B_BASES + bb] * basis[(bb * 2 + ii) * C_DIM + c];
            ws[OFF_WT + idx] = acc;
        }
    } else {
        for (int i = tid; i < NBUCK; i += 256) ((int*)(ws + OFF_ECUR))[i] = 0;
    }
}

// K2: node scan (block 0) + wq/wk/le projections (blocks 1..18)
__global__ __launch_bounds__(256) void k_scanproj(const float* __restrict__ q_att,
                                                  const float* __restrict__ k_att,
                                                  const float* __restrict__ e_att,
                                                  const float* __restrict__ lin_edge_W,
                                                  float* __restrict__ ws) {
    int b = blockIdx.x, tid = threadIdx.x;
    int lane = tid & 63, wv = tid >> 6;
    if (b == 0) {
        __shared__ int lh[NB_HIST * 4];
        __shared__ int basel[4];
        const int* hblk = (const int*)(ws + OFF_HBLK);
        for (int i = tid; i < NB_HIST * 4; i += 256) lh[i] = hblk[i];
        __syncthreads();
        __shared__ int tot[4];
        if (tid < 4) {
            int run = 0;
            for (int bb = 0; bb < NB_HIST; ++bb) {
                int v = lh[bb * 4 + tid];
                lh[bb * 4 + tid] = run;
                run += v;
            }
            tot[tid] = run;
        }
        __syncthreads();
        if (tid == 0) {
            int* meta = (int*)(ws + OFF_META);
            int t0 = tot[0], t1 = tot[1], t2 = tot[2], t3 = tot[3];
            int b1 = ((t0 + 63) >> 6) << 6;
            int b2 = b1 + (((t1 + 63) >> 6) << 6);
            int b3 = b2 + (((t2 + 63) >> 6) << 6);
            meta[0] = t0; meta[1] = t1; meta[2] = t2; meta[3] = t3;
            meta[4] = 0;  meta[5] = b1; meta[6] = b2; meta[7] = b3;
            basel[0] = 0; basel[1] = b1; basel[2] = b2; basel[3] = b3;
        }
        __syncthreads();
        for (int i = tid; i < NB_HIST * 4; i += 256)
            ((int*)(ws + OFF_BBASE))[i] = basel[i & 3] + lh[i];
    } else {
        int u = (b - 1) * 4 + wv;    // [0, 72)
        if (u < RI2) {
            const float* wr = ws + OFF_WT + u * C_DIM;
            float w1 = wr[lane], w2 = wr[64 + lane];
            float aq = w1 * q_att[lane] + w2 * q_att[64 + lane];
            float ak = w1 * k_att[lane] + w2 * k_att[64 + lane];
            #pragma unroll
            for (int off = 32; off; off >>= 1) {
                aq += __shfl_xor(aq, off, 64);
                ak += __shfl_xor(ak, off, 64);
            }
            if (lane == 0) { ws[OFF_WQ + u] = aq; ws[OFF_WK + u] = ak; }
        } else if (u < 72) {
            int j = u - RI2;
            const float* er = lin_edge_W + j * C_DIM;
            float a = er[lane] * e_att[lane] + er[64 + lane] * e_att[64 + lane];
            #pragma unroll
            for (int off = 32; off; off >>= 1) a += __shfl_xor(a, off, 64);
            if (lane == 0) ws[OFF_LE + j] = a;
        }
    }
}

// K3: node permutation — ballots + LDS partials, atomic-free, deterministic
__global__ __launch_bounds__(256) void k_perm(const int* __restrict__ node_type,
                                              float* __restrict__ ws) {
    __shared__ int wcnt[4][4];
    int tid = threadIdx.x;
    int lane = tid & 63, wv = tid >> 6;
    int n = blockIdx.x * 256 + tid;
    bool active = n < N_NODES;
    int ty = active ? node_type[n] : -1;
    int myrank = 0;
    #pragma unroll
    for (int t = 0; t < 4; ++t) {
        unsigned long long m = __ballot(ty == t);
        if (lane == 0) wcnt[wv][t] = __popcll(m);
        if (ty == t) myrank = __popcll(m & ((1ULL << lane) - 1ULL));
    }
    __syncthreads();
    if (active) {
        int pre = 0;
        for (int w2 = 0; w2 < wv; ++w2) pre += wcnt[w2][ty];
        int p = ((const int*)(ws + OFF_BBASE))[blockIdx.x * 4 + ty] + pre + myrank;
        ((int*)(ws + OFF_PERM))[n] = p;
        ((int*)(ws + OFF_INV))[p] = n;
    }
}

// K4: single-pass bucketed scatter — LDS hist, chunk reservation, record stores
__global__ __launch_bounds__(256) void k_escatter(const float* __restrict__ x,
                                                  const int* __restrict__ edge_index,
                                                  const int* __restrict__ edge_type,
                                                  const float* __restrict__ edge_attr,
                                                  float* __restrict__ ws) {
    __shared__ int hist[NBUCK];
    __shared__ int sbase[NBUCK];
    __shared__ float swq[RI2], swk[RI2], sle[2];
    int tid = threadIdx.x;
    for (int i = tid; i < NBUCK; i += 256) hist[i] = 0;
    if (tid < RI2) { swq[tid] = ws[OFF_WQ + tid]; swk[tid] = ws[OFF_WK + tid]; }
    if (tid < 2) sle[tid] = ws[OFF_LE + tid];
    __syncthreads();

    const int* perm = (const int*)(ws + OFF_PERM);
    int base = blockIdx.x * EPB;
    int   rb[8], rm[8];
    float rex[8], rsx[8], rsy[8];
    #pragma unroll
    for (int k = 0; k < 8; ++k) {
        int e = base + k * 256 + tid;
        rb[k] = -1;
        if (e < N_EDGES) {
            int src = edge_index[e];
            int dst = edge_index[N_EDGES + e];
            int r   = edge_type[e];
            int p   = perm[dst];
            float2 ea = *(const float2*)(edge_attr + 2 * e);
            float2 xs = *(const float2*)(x + 2 * src);
            float2 xd = *(const float2*)(x + 2 * dst);
            float alpha = xd.x * swq[2 * r] + xd.y * swq[2 * r + 1]
                        + xs.x * swk[2 * r] + xs.y * swk[2 * r + 1]
                        + ea.x * sle[0]     + ea.y * sle[1];
            alpha = alpha > 0.f ? alpha : 0.2f * alpha;
            float ex = __expf(alpha);
            rb[k]  = p >> 6;
            rm[k]  = (r << 6) | (p & 63);
            rex[k] = ex;
            rsx[k] = ex * xs.x;
            rsy[k] = ex * xs.y;
            atomicAdd(&hist[rb[k]], 1);
        }
    }
    __syncthreads();
    int* gcur = (int*)(ws + OFF_ECUR);
    for (int i = tid; i < NBUCK; i += 256) {
        int c = hist[i];
        sbase[i] = (c > 0) ? atomicAdd(&gcur[i], c) : 0;
    }
    __syncthreads();
    float4* rec = (float4*)(ws + OFF_EREC);
    #pragma unroll
    for (int k = 0; k < 8; ++k) {
        if (rb[k] >= 0) {
            int slot = atomicAdd(&sbase[rb[k]], 1);
            rec[(size_t)rb[k] * CAP + slot] =
                make_float4(__int_as_float(rm[k]), rex[k], rsx[k], rsy[k]);
        }
    }
}

// K5: fused node pass v2 — 39 KB LDS, natural VGPR alloc (124 <= 128 -> 4 blocks/CU)
__global__ __launch_bounds__(256) void k_node(
        const float* __restrict__ ws, const float* __restrict__ conv_bias,
        const float* __restrict__ lin0_W, const float* __restrict__ lin0_b,
        const float* __restrict__ lin1_W, const float* __restrict__ lin1_b,
        const float* __restrict__ lin2_W, const float* __restrict__ lin2_b,
        const float* __restrict__ fin_W,  const float* __restrict__ fin_b,
        float* __restrict__ out) {
    __shared__ float L[LDS_FLOATS];
    int tid  = threadIdx.x;
    int lane = tid & 63;
    int wv   = tid >> 6;
    int p0   = blockIdx.x * 64;

    const int* meta = (const int*)(ws + OFF_META);
    int b1 = meta[5], b2 = meta[6], b3 = meta[7];
    int t  = (p0 >= b1) + (p0 >= b2) + (p0 >= b3);   // block-uniform
    int bp = meta[4 + t];
    int cnt = meta[t];

    // ---------- phase 0: zero sT + den, stage FW/FB, wT chunk 0
    for (int i = tid; i < RI2 * 68; i += 256) L[ST + i] = 0.f;
    if (tid < 64) L[SM_DINV + tid] = 0.f;
    if (tid >= 64 && tid < 142) {
        int i = tid - 64;
        if (i < 76) L[SM_FW + i] = fin_W[t * 76 + i];
        else        L[SM_FB + i - 76] = fin_b[t * 2 + i - 76];
    }
    const float* wT_g = ws + OFF_WT;
    for (int i4 = tid; i4 < 448; i4 += 256) {
        float4 v = ((const float4*)wT_g)[i4];
        *(float4*)&L[CH + i4 * 4] = v;
    }
    __syncthreads();

    // ---------- phase 1: accumulate this bucket's edge records (LDS atomics)
    {
        int ecnt = ((const int*)(ws + OFF_ECUR))[blockIdx.x];
        const float4* rec = (const float4*)(ws + OFF_EREC) + (size_t)blockIdx.x * CAP;
        for (int i = tid; i < ecnt; i += 256) {
            float4 v = rec[i];
            int m = __float_as_int(v.x);
            int n = m & 63, r = m >> 6;
            atomicAdd(&L[ST + (2 * r) * 68 + n],     v.z);
            atomicAdd(&L[ST + (2 * r + 1) * 68 + n], v.w);
            atomicAdd(&L[SM_DINV + n],               v.y);
        }
    }
    __syncthreads();
    if (tid < 64) L[SM_DINV + tid] = 1.0f / (L[SM_DINV + tid] + 1e-16f);

    // ---------- GEMM1: H[64n x 128c] = sT x wT ; wave c-slice 32, lane 4n x 8c
    int ng = lane & 15, cg_ = lane >> 4;
    int c0 = wv * 32 + cg_ * 8;
    float acc[32];
    #pragma unroll
    for (int i = 0; i < 32; ++i) acc[i] = 0.f;
    int cur = 0;
    for (int q = 0; q < 5; ++q) {
        float4 pf0, pf1;
        if (q < 4) {
            const float4* src = (const float4*)(wT_g + (q + 1) * 1792);
            pf0 = src[tid];
            if (tid < 192) pf1 = src[tid + 256];
        }
        const float* wb = &L[CH + cur * 1792];
        #pragma unroll
        for (int kk = 0; kk < 14; ++kk) {
            float4 a4 = *(const float4*)&L[ST + (q * 14 + kk) * 68 + ng * 4];
            float4 wa = *(const float4*)&wb[kk * 128 + c0];
            float4 wc = *(const float4*)&wb[kk * 128 + c0 + 4];
            float a_[4] = {a4.x, a4.y, a4.z, a4.w};
            float w_[8] = {wa.x, wa.y, wa.z, wa.w, wc.x, wc.y, wc.z, wc.w};
            #pragma unroll
            for (int ni = 0; ni < 4; ++ni)
                #pragma unroll
                for (int ci = 0; ci < 8; ++ci)
                    acc[ni * 8 + ci] += a_[ni] * w_[ci];
        }
        if (q < 4) {
            float* dstb = &L[CH + (cur ^ 1) * 1792];
            *(float4*)&dstb[tid * 4] = pf0;
            if (tid < 192) *(float4*)&dstb[(tid + 256) * 4] = pf1;
        }
        cur ^= 1;
        __syncthreads();
    }
    // all waves past final barrier: CH + ST dead -> H may overwrite [0,8192)

    // epilogue 1: h = relu(acc*dinv + cb) -> H[c][n]  (conv_bias from global)
    {
        float4 dv = *(const float4*)&L[SM_DINV + ng * 4];
        float d_[4] = {dv.x, dv.y, dv.z, dv.w};
        #pragma unroll
        for (int ci = 0; ci < 8; ++ci) {
            float cb = conv_bias[c0 + ci];
            float4 hv;
            float h0 = acc[0 * 8 + ci] * d_[0] + cb;
            float h1 = acc[1 * 8 + ci] * d_[1] + cb;
            float h2 = acc[2 * 8 + ci] * d_[2] + cb;
            float h3 = acc[3 * 8 + ci] * d_[3] + cb;
            hv.x = h0 > 0.f ? h0 : 0.f;
            hv.y = h1 > 0.f ? h1 : 0.f;
            hv.z = h2 > 0.f ? h2 : 0.f;
            hv.w = h3 > 0.f ? h3 : 0.f;
            *(float4*)&L[HH + (c0 + ci) * 64 + ng * 4] = hv;
        }
    }
    __syncthreads();   // H complete

    // ---------- GEMM2: y0[64n x 48j] = H x W0 ; waves 0..2, wave 3 idles
    const float* W0g = lin0_W + t * C_DIM * HL_DIM;
    int jg = lane >> 4;
    int j0 = wv * 16 + jg * 4;
    float acc2[16];
    #pragma unroll
    for (int i = 0; i < 16; ++i) acc2[i] = 0.f;
    for (int q = 0; q < 4; ++q) {
        for (int i = tid; i < 1216; i += 256) {
            int cc = i / 38, j = i - cc * 38;
            L[W0Q + cc * 40 + j] = W0g[q * 1216 + i];
        }
        __syncthreads();
        if (wv < 3) {
            #pragma unroll 4
            for (int kk = 0; kk < 32; ++kk) {
                int c = q * 32 + kk;
                float4 a4 = *(const float4*)&L[HH + c * 64 + ng * 4];
                float4 w4 = *(const float4*)&L[W0Q + kk * 40 + j0];
                float a_[4] = {a4.x, a4.y, a4.z, a4.w};
                float w_[4] = {w4.x, w4.y, w4.z, w4.w};
                #pragma unroll
                for (int ni = 0; ni < 4; ++ni)
                    #pragma unroll
                    for (int ji = 0; ji < 4; ++ji)
                        acc2[ni * 4 + ji] += a_[ni] * w_[ji];
            }
        }
        __syncthreads();
    }
    // epilogue 2 (waves 0..2): relu(y0 + b0) -> y0T[j][n] over dead H
    if (wv < 3) {
        #pragma unroll
        for (int ji = 0; ji < 4; ++ji) {
            int j = j0 + ji;
            float b = (j < HL_DIM) ? lin0_b[t * HL_DIM + j] : 0.f;
            float4 yv;
            float y0 = acc2[0 * 4 + ji] + b;
            float y1 = acc2[1 * 4 + ji] + b;
            float y2 = acc2[2 * 4 + ji] + b;
            float y3 = acc2[3 * 4 + ji] + b;
            yv.x = y0 > 0.f ? y0 : 0.f;
            yv.y = y1 > 0.f ? y1 : 0.f;
            yv.z = y2 > 0.f ? y2 : 0.f;
            yv.w = y3 > 0.f ? y3 : 0.f;
            *(float4*)&L[Y0T + j * 68 + ng * 4] = yv;
        }
    }
    // stage W1/W2 into dead H region (disjoint from Y0T)
    {
        const float* W1g = lin1_W + t * HL_DIM * HL_DIM;
        const float* W2g = lin2_W + t * HL_DIM * HL_DIM;
        for (int i = tid; i < 1444; i += 256) {
            int cc = i / 38, j = i - cc * 38;
            L[W1S + cc * 40 + j] = W1g[i];
            L[W2S + cc * 40 + j] = W2g[i];
        }
    }
    __syncthreads();

    // ---------- GEMM3: y1 = y0 x W1 (k=38, resident) ; waves 0..2
    float acc3[16];
    #pragma unroll
    for (int i = 0; i < 16; ++i) acc3[i] = 0.f;
    if (wv < 3) {
        #pragma unroll 2
        for (int kk = 0; kk < HL_DIM; ++kk) {
            float4 a4 = *(const float4*)&L[Y0T + kk * 68 + ng * 4];
            float4 w4 = *(const float4*)&L[W1S + kk * 40 + j0];
            float a_[4] = {a4.x, a4.y, a4.z, a4.w};
            float w_[4] = {w4.x, w4.y, w4.z, w4.w};
            #pragma unroll
            for (int ni = 0; ni < 4; ++ni)
                #pragma unroll
                for (int ji = 0; ji < 4; ++ji)
                    acc3[ni * 4 + ji] += a_[ni] * w_[ji];
        }
        #pragma unroll
        for (int ji = 0; ji < 4; ++ji) {
            int j = j0 + ji;
            float b = (j < HL_DIM) ? lin1_b[t * HL_DIM + j] : 0.f;
            float4 yv;
            float y0 = acc3[0 * 4 + ji] + b;
            float y1 = acc3[1 * 4 + ji] + b;
            float y2 = acc3[2 * 4 + ji] + b;
            float y3 = acc3[3 * 4 + ji] + b;
            yv.x = y0 > 0.f ? y0 : 0.f;
            yv.y = y1 > 0.f ? y1 : 0.f;
            yv.z = y2 > 0.f ? y2 : 0.f;
            yv.w = y3 > 0.f ? y3 : 0.f;
            *(float4*)&L[Y1T + j * 68 + ng * 4] = yv;
        }
    }
    __syncthreads();

    // ---------- GEMM4: y2 = y1 x W2 (no relu) ; waves 0..2 ; y2T over dead Y0T
    if (wv < 3) {
        float acc4[16];
        #pragma unroll
        for (int i = 0; i < 16; ++i) acc4[i] = 0.f;
        #pragma unroll 2
        for (int kk = 0; kk < HL_DIM; ++kk) {
            float4 a4 = *(const float4*)&L[Y1T + kk * 68 + ng * 4];
            float4 w4 = *(const float4*)&L[W2S + kk * 40 + j0];
            float a_[4] = {a4.x, a4.y, a4.z, a4.w};
            float w_[4] = {w4.x, w4.y, w4.z, w4.w};
            #pragma unroll
            for (int ni = 0; ni < 4; ++ni)
                #pragma unroll
                for (int ji = 0; ji < 4; ++ji)
                    acc4[ni * 4 + ji] += a_[ni] * w_[ji];
        }
        #pragma unroll
        for (int ji = 0; ji < 4; ++ji) {
            int j = j0 + ji;
            float b = (j < HL_DIM) ? lin2_b[t * HL_DIM + j] : 0.f;
            float4 yv;
            yv.x = acc4[0 * 4 + ji] + b;
            yv.y = acc4[1 * 4 + ji] + b;
            yv.z = acc4[2 * 4 + ji] + b;
            yv.w = acc4[3 * 4 + ji] + b;
            *(float4*)&L[Y2T + j * 68 + ng * 4] = yv;
        }
    }
    __syncthreads();

    // ---------- final: fin [38]->[2], thread-per-node (wave 0)
    if (tid < 64) {
        int p = p0 + tid;
        bool valid = (p - bp) < cnt;
        float o0 = L[SM_FB], o1 = L[SM_FB + 1];
        for (int jj = 0; jj < HL_DIM; ++jj) {
            float v = L[Y2T + jj * 68 + tid];
            float2 f = *(const float2*)&L[SM_FW + jj * 2];
            o0 += v * f.x;
            o1 += v * f.y;
        }
        if (t == 0) o1 = fabsf(o1);
        if (valid) {
            int orig = ((const int*)(ws + OFF_INV))[p];
            ((float2*)out)[orig] = make_float2(o0, o1);
        }
    }
}

extern "C" void kernel_launch(void* const* d_in, const int* in_sizes, int n_in,
                              void* d_out, int out_size, void* d_ws, size_t ws_size,
                              hipStream_t stream) {
    const float* x          = (const float*)d_in[0];
    const int*   edge_index = (const int*)  d_in[1];
    const int*   edge_type  = (const int*)  d_in[2];
    const float* edge_attr  = (const float*)d_in[3];
    const int*   node_type  = (const int*)  d_in[4];
    const float* basis      = (const float*)d_in[5];
    const float* att_rel    = (const float*)d_in[6];
    const float* q_att      = (const float*)d_in[7];
    const float* k_att      = (const float*)d_in[8];
    const float* e_att      = (const float*)d_in[9];
    const float* lin_edge_W = (const float*)d_in[10];
    const float* conv_bias  = (const float*)d_in[11];
    const float* lin0_W     = (const float*)d_in[12];
    const float* lin0_b     = (const float*)d_in[13];
    const float* lin1_W     = (const float*)d_in[14];
    const float* lin1_b     = (const float*)d_in[15];
    const float* lin2_W     = (const float*)d_in[16];
    const float* lin2_b     = (const float*)d_in[17];
    const float* fin_W      = (const float*)d_in[18];
    const float* fin_b      = (const float*)d_in[19];

    float* ws  = (float*)d_ws;
    float* out = (float*)d_out;

    k_init    <<<NB_HIST + 35 + 1, 256, 0, stream>>>(node_type, basis, att_rel, ws);
    k_scanproj<<<19, 256, 0, stream>>>(q_att, k_att, e_att, lin_edge_W, ws);
    k_perm    <<<NB_HIST, 256, 0, stream>>>(node_type, ws);
    k_escatter<<<NB_HIST, 256, 0, stream>>>(x, edge_index, edge_type, edge_attr, ws);
    k_node    <<<NBUCK, 256, 0, stream>>>(ws, conv_bias,
                                          lin0_W, lin0_b, lin1_W, lin1_b,
                                          lin2_W, lin2_b, fin_W, fin_b, out);
}

// Round 12
// 176.127 us; speedup vs baseline: 1.4379x; 1.0090x over previous
//
#include <hip/hip_runtime.h>
#include <math.h>

#define N_NODES 50000
#define N_EDGES 400000
#define R_REL   35
#define B_BASES 12
#define C_DIM   128
#define HL_DIM  38
#define RI2     70
#define NP      50304         // padded permuted node space (mult of 64)
#define NB_HIST 196           // ceil(50000/256)
#define NBUCK   786           // NP/64 — one bucket per k_node tile
#define EPB     2048          // edges per scatter block (196*2048 >= 400000)
#define CAP     704           // fixed bucket segment capacity (mean 512, 8.5 sigma)

// ---- ws float offsets ----
#define OFF_WT     0          // w[ri][c] = [70][128] = 8960
#define OFF_WQ     8960       // [70]
#define OFF_WK     9030       // [70]
#define OFF_LE     9100       // [2]
#define OFF_META   9104       // 16 ints: counts[4]@0, base_pad[4]@4
#define OFF_HBLK   9120       // int[196][4]
#define OFF_PERM   10688      // int[50000]
#define OFF_INV    60688      // int[NP]
#define OFF_ECUR   110992     // int[786] global bucket cursors
#define OFF_EREC   111780     // float4[786*704]  (111780 % 4 == 0 -> 16B aligned)

// ---- k_node LDS float offsets (region aliasing, 39.06 KB total) ----
#define CH    0
#define ST    3584
#define HH    0
#define Y0T   0
#define W1S   3264
#define W2S   4784
#define Y1T   6304
#define Y2T   0
#define W0Q   8344
#define SM_DINV 9624   // [64]
#define SM_FW   9688   // [76]
#define SM_FB   9764   // [2]
#define LDS_FLOATS 9766

// K1: node hist (0..195) + wT init (196..230) + cursor zero (231) + projections (232..267)
__global__ __launch_bounds__(256) void k_init(const int* __restrict__ node_type,
                                              const float* __restrict__ basis,
                                              const float* __restrict__ att_rel,
                                              const float* __restrict__ q_att,
                                              const float* __restrict__ k_att,
                                              const float* __restrict__ e_att,
                                              const float* __restrict__ lin_edge_W,
                                              float* __restrict__ ws) {
    int b = blockIdx.x, tid = threadIdx.x;
    if (b < NB_HIST) {
        __shared__ int lh[4];
        if (tid < 4) lh[tid] = 0;
        __syncthreads();
        int i = b * 256 + tid;
        if (i < N_NODES) atomicAdd(&lh[node_type[i]], 1);
        __syncthreads();
        if (tid < 4) ((int*)(ws + OFF_HBLK))[b * 4 + tid] = lh[tid];
    } else if (b < NB_HIST + 35) {
        int idx = (b - NB_HIST) * 256 + tid;
        if (idx < RI2 * C_DIM) {
            int c  = idx & (C_DIM - 1);
            int ri = idx >> 7;
            int r = ri >> 1, ii = ri & 1;
            float acc = 0.f;
            #pragma unroll
            for (int bb = 0; bb < B_BASES; ++bb)
                acc += att_rel[r * B_BASES + bb] * basis[(bb * 2 + ii) * C_DIM + c];
            ws[OFF_WT + idx] = acc;
        }
    } else if (b == NB_HIST + 35) {
        for (int i = tid; i < NBUCK; i += 256) ((int*)(ws + OFF_ECUR))[i] = 0;
    } else {
        // projections, independent of wT: unit u = (b-232)*4 + wave, u in [0,144)
        int lane = tid & 63, wv = tid >> 6;
        int u = (b - (NB_HIST + 36)) * 4 + wv;
        if (u < 2 * RI2) {
            int ri = (u < RI2) ? u : (u - RI2);
            int r = ri >> 1, ii = ri & 1;
            const float* av = att_rel + r * B_BASES;
            const float* bs = basis + ii * C_DIM;
            float w1 = 0.f, w2 = 0.f;
            #pragma unroll
            for (int bb = 0; bb < B_BASES; ++bb) {
                float a = av[bb];
                w1 += a * bs[bb * 2 * C_DIM + lane];
                w2 += a * bs[bb * 2 * C_DIM + 64 + lane];
            }
            const float* qk = (u < RI2) ? q_att : k_att;
            float s = w1 * qk[lane] + w2 * qk[64 + lane];
            #pragma unroll
            for (int off = 32; off; off >>= 1) s += __shfl_xor(s, off, 64);
            if (lane == 0) ws[((u < RI2) ? OFF_WQ : OFF_WK) + ri] = s;
        } else if (u < 2 * RI2 + 2) {
            int j = u - 2 * RI2;
            const float* er = lin_edge_W + j * C_DIM;
            float s = er[lane] * e_att[lane] + er[64 + lane] * e_att[64 + lane];
            #pragma unroll
            for (int off = 32; off; off >>= 1) s += __shfl_xor(s, off, 64);
            if (lane == 0) ws[OFF_LE + j] = s;
        }
    }
}

// K2: permutation — redundant per-block scan of HBLK + ballot ranks; block 0 writes META
__global__ __launch_bounds__(256) void k_perm(const int* __restrict__ node_type,
                                              float* __restrict__ ws) {
    __shared__ int lh[NB_HIST * 4];
    __shared__ int pre[4], tot[4], basel[4];
    __shared__ int wcnt[4][4];
    int tid = threadIdx.x;
    int lane = tid & 63, wv = tid >> 6;
    const int* hblk = (const int*)(ws + OFF_HBLK);
    for (int i = tid; i < NB_HIST * 4; i += 256) lh[i] = hblk[i];
    __syncthreads();
    if (tid < 4) {
        int run = 0, mypre = 0;
        for (int bb = 0; bb < NB_HIST; ++bb) {
            if (bb == (int)blockIdx.x) mypre = run;
            run += lh[bb * 4 + tid];
        }
        pre[tid] = mypre;
        tot[tid] = run;
    }
    __syncthreads();
    if (tid == 0) {
        int t0 = tot[0], t1 = tot[1], t2 = tot[2];
        int b1 = ((t0 + 63) >> 6) << 6;
        int b2 = b1 + (((t1 + 63) >> 6) << 6);
        int b3 = b2 + (((t2 + 63) >> 6) << 6);
        basel[0] = 0; basel[1] = b1; basel[2] = b2; basel[3] = b3;
        if (blockIdx.x == 0) {
            int* meta = (int*)(ws + OFF_META);
            meta[0] = t0; meta[1] = t1; meta[2] = t2; meta[3] = tot[3];
            meta[4] = 0;  meta[5] = b1; meta[6] = b2; meta[7] = b3;
        }
    }
    __syncthreads();
    int n = blockIdx.x * 256 + tid;
    bool active = n < N_NODES;
    int ty = active ? node_type[n] : -1;
    int myrank = 0;
    #pragma unroll
    for (int t = 0; t < 4; ++t) {
        unsigned long long m = __ballot(ty == t);
        if (lane == 0) wcnt[wv][t] = __popcll(m);
        if (ty == t) myrank = __popcll(m & ((1ULL << lane) - 1ULL));
    }
    __syncthreads();
    if (active) {
        int prew = 0;
        for (int w2 = 0; w2 < wv; ++w2) prew += wcnt[w2][ty];
        int p = basel[ty] + pre[ty] + prew + myrank;
        ((int*)(ws + OFF_PERM))[n] = p;
        ((int*)(ws + OFF_INV))[p] = n;
    }
}

// K3: single-pass bucketed scatter — LDS hist, chunk reservation, record stores
__global__ __launch_bounds__(256) void k_escatter(const float* __restrict__ x,
                                                  const int* __restrict__ edge_index,
                                                  const int* __restrict__ edge_type,
                                                  const float* __restrict__ edge_attr,
                                                  float* __restrict__ ws) {
    __shared__ int hist[NBUCK];
    __shared__ int sbase[NBUCK];
    __shared__ float swq[RI2], swk[RI2], sle[2];
    int tid = threadIdx.x;
    for (int i = tid; i < NBUCK; i += 256) hist[i] = 0;
    if (tid < RI2) { swq[tid] = ws[OFF_WQ + tid]; swk[tid] = ws[OFF_WK + tid]; }
    if (tid < 2) sle[tid] = ws[OFF_LE + tid];
    __syncthreads();

    const int* perm = (const int*)(ws + OFF_PERM);
    int base = blockIdx.x * EPB;
    int   rb[8], rm[8];
    float rex[8], rsx[8], rsy[8];
    #pragma unroll
    for (int k = 0; k < 8; ++k) {
        int e = base + k * 256 + tid;
        rb[k] = -1;
        if (e < N_EDGES) {
            int src = edge_index[e];
            int dst = edge_index[N_EDGES + e];
            int r   = edge_type[e];
            int p   = perm[dst];
            float2 ea = *(const float2*)(edge_attr + 2 * e);
            float2 xs = *(const float2*)(x + 2 * src);
            float2 xd = *(const float2*)(x + 2 * dst);
            float alpha = xd.x * swq[2 * r] + xd.y * swq[2 * r + 1]
                        + xs.x * swk[2 * r] + xs.y * swk[2 * r + 1]
                        + ea.x * sle[0]     + ea.y * sle[1];
            alpha = alpha > 0.f ? alpha : 0.2f * alpha;
            float ex = __expf(alpha);
            rb[k]  = p >> 6;
            rm[k]  = (r << 6) | (p & 63);
            rex[k] = ex;
            rsx[k] = ex * xs.x;
            rsy[k] = ex * xs.y;
            atomicAdd(&hist[rb[k]], 1);
        }
    }
    __syncthreads();
    int* gcur = (int*)(ws + OFF_ECUR);
    for (int i = tid; i < NBUCK; i += 256) {
        int c = hist[i];
        sbase[i] = (c > 0) ? atomicAdd(&gcur[i], c) : 0;
    }
    __syncthreads();
    float4* rec = (float4*)(ws + OFF_EREC);
    #pragma unroll
    for (int k = 0; k < 8; ++k) {
        if (rb[k] >= 0) {
            int slot = atomicAdd(&sbase[rb[k]], 1);
            rec[(size_t)rb[k] * CAP + slot] =
                make_float4(__int_as_float(rm[k]), rex[k], rsx[k], rsy[k]);
        }
    }
}

// K4: fused node pass — 39 KB LDS, natural VGPR alloc
__global__ __launch_bounds__(256) void k_node(
        const float* __restrict__ ws, const float* __restrict__ conv_bias,
        const float* __restrict__ lin0_W, const float* __restrict__ lin0_b,
        const float* __restrict__ lin1_W, const float* __restrict__ lin1_b,
        const float* __restrict__ lin2_W, const float* __restrict__ lin2_b,
        const float* __restrict__ fin_W,  const float* __restrict__ fin_b,
        float* __restrict__ out) {
    __shared__ float L[LDS_FLOATS];
    int tid  = threadIdx.x;
    int lane = tid & 63;
    int wv   = tid >> 6;
    int p0   = blockIdx.x * 64;

    const int* meta = (const int*)(ws + OFF_META);
    int b1 = meta[5], b2 = meta[6], b3 = meta[7];
    int t  = (p0 >= b1) + (p0 >= b2) + (p0 >= b3);   // block-uniform
    int bp = meta[4 + t];
    int cnt = meta[t];

    // ---------- phase 0: zero sT + den, stage FW/FB, wT chunk 0
    for (int i = tid; i < RI2 * 68; i += 256) L[ST + i] = 0.f;
    if (tid < 64) L[SM_DINV + tid] = 0.f;
    if (tid >= 64 && tid < 142) {
        int i = tid - 64;
        if (i < 76) L[SM_FW + i] = fin_W[t * 76 + i];
        else        L[SM_FB + i - 76] = fin_b[t * 2 + i - 76];
    }
    const float* wT_g = ws + OFF_WT;
    for (int i4 = tid; i4 < 448; i4 += 256) {
        float4 v = ((const float4*)wT_g)[i4];
        *(float4*)&L[CH + i4 * 4] = v;
    }
    __syncthreads();

    // ---------- phase 1: accumulate this bucket's edge records (LDS atomics)
    {
        int ecnt = ((const int*)(ws + OFF_ECUR))[blockIdx.x];
        const float4* rec = (const float4*)(ws + OFF_EREC) + (size_t)blockIdx.x * CAP;
        for (int i = tid; i < ecnt; i += 256) {
            float4 v = rec[i];
            int m = __float_as_int(v.x);
            int n = m & 63, r = m >> 6;
            atomicAdd(&L[ST + (2 * r) * 68 + n],     v.z);
            atomicAdd(&L[ST + (2 * r + 1) * 68 + n], v.w);
            atomicAdd(&L[SM_DINV + n],               v.y);
        }
    }
    __syncthreads();
    if (tid < 64) L[SM_DINV + tid] = 1.0f / (L[SM_DINV + tid] + 1e-16f);

    // ---------- GEMM1: H[64n x 128c] = sT x wT ; wave c-slice 32, lane 4n x 8c
    int ng = lane & 15, cg_ = lane >> 4;
    int c0 = wv * 32 + cg_ * 8;
    float acc[32];
    #pragma unroll
    for (int i = 0; i < 32; ++i) acc[i] = 0.f;
    int cur = 0;
    for (int q = 0; q < 5; ++q) {
        float4 pf0, pf1;
        if (q < 4) {
            const float4* src = (const float4*)(wT_g + (q + 1) * 1792);
            pf0 = src[tid];
            if (tid < 192) pf1 = src[tid + 256];
        }
        const float* wb = &L[CH + cur * 1792];
        #pragma unroll
        for (int kk = 0; kk < 14; ++kk) {
            float4 a4 = *(const float4*)&L[ST + (q * 14 + kk) * 68 + ng * 4];
            float4 wa = *(const float4*)&wb[kk * 128 + c0];
            float4 wc = *(const float4*)&wb[kk * 128 + c0 + 4];
            float a_[4] = {a4.x, a4.y, a4.z, a4.w};
            float w_[8] = {wa.x, wa.y, wa.z, wa.w, wc.x, wc.y, wc.z, wc.w};
            #pragma unroll
            for (int ni = 0; ni < 4; ++ni)
                #pragma unroll
                for (int ci = 0; ci < 8; ++ci)
                    acc[ni * 8 + ci] += a_[ni] * w_[ci];
        }
        if (q < 4) {
            float* dstb = &L[CH + (cur ^ 1) * 1792];
            *(float4*)&dstb[tid * 4] = pf0;
            if (tid < 192) *(float4*)&dstb[(tid + 256) * 4] = pf1;
        }
        cur ^= 1;
        __syncthreads();
    }

    // epilogue 1: h = relu(acc*dinv + cb) -> H[c][n]
    {
        float4 dv = *(const float4*)&L[SM_DINV + ng * 4];
        float d_[4] = {dv.x, dv.y, dv.z, dv.w};
        #pragma unroll
        for (int ci = 0; ci < 8; ++ci) {
            float cb = conv_bias[c0 + ci];
            float4 hv;
            float h0 = acc[0 * 8 + ci] * d_[0] + cb;
            float h1 = acc[1 * 8 + ci] * d_[1] + cb;
            float h2 = acc[2 * 8 + ci] * d_[2] + cb;
            float h3 = acc[3 * 8 + ci] * d_[3] + cb;
            hv.x = h0 > 0.f ? h0 : 0.f;
            hv.y = h1 > 0.f ? h1 : 0.f;
            hv.z = h2 > 0.f ? h2 : 0.f;
            hv.w = h3 > 0.f ? h3 : 0.f;
            *(float4*)&L[HH + (c0 + ci) * 64 + ng * 4] = hv;
        }
    }
    __syncthreads();   // H complete

    // ---------- GEMM2: y0[64n x 48j] = H x W0 ; waves 0..2, wave 3 idles
    const float* W0g = lin0_W + t * C_DIM * HL_DIM;
    int jg = lane >> 4;
    int j0 = wv * 16 + jg * 4;
    float acc2[16];
    #pragma unroll
    for (int i = 0; i < 16; ++i) acc2[i] = 0.f;
    for (int q = 0; q < 4; ++q) {
        for (int i = tid; i < 1216; i += 256) {
            int cc = i / 38, j = i - cc * 38;
            L[W0Q + cc * 40 + j] = W0g[q * 1216 + i];
        }
        __syncthreads();
        if (wv < 3) {
            #pragma unroll 4
            for (int kk = 0; kk < 32; ++kk) {
                int c = q * 32 + kk;
                float4 a4 = *(const float4*)&L[HH + c * 64 + ng * 4];
                float4 w4 = *(const float4*)&L[W0Q + kk * 40 + j0];
                float a_[4] = {a4.x, a4.y, a4.z, a4.w};
                float w_[4] = {w4.x, w4.y, w4.z, w4.w};
                #pragma unroll
                for (int ni = 0; ni < 4; ++ni)
                    #pragma unroll
                    for (int ji = 0; ji < 4; ++ji)
                        acc2[ni * 4 + ji] += a_[ni] * w_[ji];
            }
        }
        __syncthreads();
    }
    if (wv < 3) {
        #pragma unroll
        for (int ji = 0; ji < 4; ++ji) {
            int j = j0 + ji;
            float b = (j < HL_DIM) ? lin0_b[t * HL_DIM + j] : 0.f;
            float4 yv;
            float y0 = acc2[0 * 4 + ji] + b;
            float y1 = acc2[1 * 4 + ji] + b;
            float y2 = acc2[2 * 4 + ji] + b;
            float y3 = acc2[3 * 4 + ji] + b;
            yv.x = y0 > 0.f ? y0 : 0.f;
            yv.y = y1 > 0.f ? y1 : 0.f;
            yv.z = y2 > 0.f ? y2 : 0.f;
            yv.w = y3 > 0.f ? y3 : 0.f;
            *(float4*)&L[Y0T + j * 68 + ng * 4] = yv;
        }
    }
    {
        const float* W1g = lin1_W + t * HL_DIM * HL_DIM;
        const float* W2g = lin2_W + t * HL_DIM * HL_DIM;
        for (int i = tid; i < 1444; i += 256) {
            int cc = i / 38, j = i - cc * 38;
            L[W1S + cc * 40 + j] = W1g[i];
            L[W2S + cc * 40 + j] = W2g[i];
        }
    }
    __syncthreads();

    // ---------- GEMM3: y1 = y0 x W1 ; waves 0..2
    float acc3[16];
    #pragma unroll
    for (int i = 0; i < 16; ++i) acc3[i] = 0.f;
    if (wv < 3) {
        #pragma unroll 2
        for (int kk = 0; kk < HL_DIM; ++kk) {
            float4 a4 = *(const float4*)&L[Y0T + kk * 68 + ng * 4];
            float4 w4 = *(const float4*)&L[W1S + kk * 40 + j0];
            float a_[4] = {a4.x, a4.y, a4.z, a4.w};
            float w_[4] = {w4.x, w4.y, w4.z, w4.w};
            #pragma unroll
            for (int ni = 0; ni < 4; ++ni)
                #pragma unroll
                for (int ji = 0; ji < 4; ++ji)
                    acc3[ni * 4 + ji] += a_[ni] * w_[ji];
        }
        #pragma unroll
        for (int ji = 0; ji < 4; ++ji) {
            int j = j0 + ji;
            float b = (j < HL_DIM) ? lin1_b[t * HL_DIM + j] : 0.f;
            float4 yv;
            float y0 = acc3[0 * 4 + ji] + b;
            float y1 = acc3[1 * 4 + ji] + b;
            float y2 = acc3[2 * 4 + ji] + b;
            float y3 = acc3[3 * 4 + ji] + b;
            yv.x = y0 > 0.f ? y0 : 0.f;
            yv.y = y1 > 0.f ? y1 : 0.f;
            yv.z = y2 > 0.f ? y2 : 0.f;
            yv.w = y3 > 0.f ? y3 : 0.f;
            *(float4*)&L[Y1T + j * 68 + ng * 4] = yv;
        }
    }
    __syncthreads();

    // ---------- GEMM4: y2 = y1 x W2 (no relu) ; waves 0..2
    if (wv < 3) {
        float acc4[16];
        #pragma unroll
        for (int i = 0; i < 16; ++i) acc4[i] = 0.f;
        #pragma unroll 2
        for (int kk = 0; kk < HL_DIM; ++kk) {
            float4 a4 = *(const float4*)&L[Y1T + kk * 68 + ng * 4];
            float4 w4 = *(const float4*)&L[W2S + kk * 40 + j0];
            float a_[4] = {a4.x, a4.y, a4.z, a4.w};
            float w_[4] = {w4.x, w4.y, w4.z, w4.w};
            #pragma unroll
            for (int ni = 0; ni < 4; ++ni)
                #pragma unroll
                for (int ji = 0; ji < 4; ++ji)
                    acc4[ni * 4 + ji] += a_[ni] * w_[ji];
        }
        #pragma unroll
        for (int ji = 0; ji < 4; ++ji) {
            int j = j0 + ji;
            float b = (j < HL_DIM) ? lin2_b[t * HL_DIM + j] : 0.f;
            float4 yv;
            yv.x = acc4[0 * 4 + ji] + b;
            yv.y = acc4[1 * 4 + ji] + b;
            yv.z = acc4[2 * 4 + ji] + b;
            yv.w = acc4[3 * 4 + ji] + b;
            *(float4*)&L[Y2T + j * 68 + ng * 4] = yv;
        }
    }
    __syncthreads();

    // ---------- final: fin [38]->[2], thread-per-node (wave 0)
    if (tid < 64) {
        int p = p0 + tid;
        bool valid = (p - bp) < cnt;
        float o0 = L[SM_FB], o1 = L[SM_FB + 1];
        for (int jj = 0; jj < HL_DIM; ++jj) {
            float v = L[Y2T + jj * 68 + tid];
            float2 f = *(const float2*)&L[SM_FW + jj * 2];
            o0 += v * f.x;
            o1 += v * f.y;
        }
        if (t == 0) o1 = fabsf(o1);
        if (valid) {
            int orig = ((const int*)(ws + OFF_INV))[p];
            ((float2*)out)[orig] = make_float2(o0, o1);
        }
    }
}

extern "C" void kernel_launch(void* const* d_in, const int* in_sizes, int n_in,
                              void* d_out, int out_size, void* d_ws, size_t ws_size,
                              hipStream_t stream) {
    const float* x          = (const float*)d_in[0];
    const int*   edge_index = (const int*)  d_in[1];
    const int*   edge_type  = (const int*)  d_in[2];
    const float* edge_attr  = (const float*)d_in[3];
    const int*   node_type  = (const int*)  d_in[4];
    const float* basis      = (const float*)d_in[5];
    const float* att_rel    = (const float*)d_in[6];
    const float* q_att      = (const float*)d_in[7];
    const float* k_att      = (const float*)d_in[8];
    const float* e_att      = (const float*)d_in[9];
    const float* lin_edge_W = (const float*)d_in[10];
    const float* conv_bias  = (const float*)d_in[11];
    const float* lin0_W     = (const float*)d_in[12];
    const float* lin0_b     = (const float*)d_in[13];
    const float* lin1_W     = (const float*)d_in[14];
    const float* lin1_b     = (const float*)d_in[15];
    const float* lin2_W     = (const float*)d_in[16];
    const float* lin2_b     = (const float*)d_in[17];
    const float* fin_W      = (const float*)d_in[18];
    const float* fin_b      = (const float*)d_in[19];

    float* ws  = (float*)d_ws;
    float* out = (float*)d_out;

    k_init    <<<NB_HIST + 35 + 1 + 36, 256, 0, stream>>>(node_type, basis, att_rel,
                                                          q_att, k_att, e_att, lin_edge_W, ws);
    k_perm    <<<NB_HIST, 256, 0, stream>>>(node_type, ws);
    k_escatter<<<NB_HIST, 256, 0, stream>>>(x, edge_index, edge_type, edge_attr, ws);
    k_node    <<<NBUCK, 256, 0, stream>>>(ws, conv_bias,
                                          lin0_W, lin0_b, lin1_W, lin1_b,
                                          lin2_W, lin2_b, fin_W, fin_b, out);
}

// Round 13
// 172.946 us; speedup vs baseline: 1.4643x; 1.0184x over previous
//
#include <hip/hip_runtime.h>
#include <math.h>

#define N_NODES 50000
#define N_EDGES 400000
#define R_REL   35
#define B_BASES 12
#define C_DIM   128
#define HL_DIM  38
#define RI2     70
#define NP      50304         // padded permuted node space (mult of 64)
#define NB_HIST 196           // ceil(50000/256)
#define NBUCK   786           // NP/64 — one bucket per k_node tile
#define EPB     2048          // edges per scatter block (196*2048 >= 400000)
#define CAP     704           // fixed bucket segment capacity (mean 512, 8.5 sigma)

// ---- ws float offsets ----
#define OFF_WT     0          // w[ri][c] = [70][128] = 8960
#define OFF_WQ     8960       // [70]
#define OFF_WK     9030       // [70]
#define OFF_LE     9100       // [2]
#define OFF_META   9104       // 16 ints: counts[4]@0, base_pad[4]@4
#define OFF_HBLK   9120       // int[196][4]
#define OFF_PERM   10688      // int[50000]
#define OFF_INV    60688      // int[NP]
#define OFF_ECUR   110992     // int[786] global bucket cursors
#define OFF_EREC   111780     // float4[786*704]  (111780 % 4 == 0 -> 16B aligned)

// ---- k_node v3 LDS float offsets (76.1 KB, 2 blocks/CU; grid=786≈3/CU so fine) ----
// phase0..GEMM1 : ST [0,4760) sT[70][68] ; WT [4760,13720) wT[70][128] ; W0F [13720,18888)
// after GEMM1   : H  [0,8192) over ST+WT-head ; W1S [8192,9720) W2S [9720,11248) in dead WT
// after GEMM2   : Y0T [0,3264) over dead H ; Y1T [3264,6528) ; Y2T [0,3264) after GEMM3
#define ST    0
#define WT    4760
#define HH    0
#define Y0T   0
#define Y1T   3264
#define Y2T   0
#define W1S   8192
#define W2S   9720
#define W0F   13720
#define SM_DINV 18888  // [64]
#define SM_FW   18952  // [76]
#define SM_FB   19028  // [2]
#define LDS_FLOATS 19030

// K1: node hist (0..195) + wT init (196..230) + cursor zero (231) + projections (232..267)
__global__ __launch_bounds__(256) void k_init(const int* __restrict__ node_type,
                                              const float* __restrict__ basis,
                                              const float* __restrict__ att_rel,
                                              const float* __restrict__ q_att,
                                              const float* __restrict__ k_att,
                                              const float* __restrict__ e_att,
                                              const float* __restrict__ lin_edge_W,
                                              float* __restrict__ ws) {
    int b = blockIdx.x, tid = threadIdx.x;
    if (b < NB_HIST) {
        __shared__ int lh[4];
        if (tid < 4) lh[tid] = 0;
        __syncthreads();
        int i = b * 256 + tid;
        if (i < N_NODES) atomicAdd(&lh[node_type[i]], 1);
        __syncthreads();
        if (tid < 4) ((int*)(ws + OFF_HBLK))[b * 4 + tid] = lh[tid];
    } else if (b < NB_HIST + 35) {
        int idx = (b - NB_HIST) * 256 + tid;
        if (idx < RI2 * C_DIM) {
            int c  = idx & (C_DIM - 1);
            int ri = idx >> 7;
            int r = ri >> 1, ii = ri & 1;
            float acc = 0.f;
            #pragma unroll
            for (int bb = 0; bb < B_BASES; ++bb)
                acc += att_rel[r * B_BASES + bb] * basis[(bb * 2 + ii) * C_DIM + c];
            ws[OFF_WT + idx] = acc;
        }
    } else if (b == NB_HIST + 35) {
        for (int i = tid; i < NBUCK; i += 256) ((int*)(ws + OFF_ECUR))[i] = 0;
    } else {
        int lane = tid & 63, wv = tid >> 6;
        int u = (b - (NB_HIST + 36)) * 4 + wv;
        if (u < 2 * RI2) {
            int ri = (u < RI2) ? u : (u - RI2);
            int r = ri >> 1, ii = ri & 1;
            const float* av = att_rel + r * B_BASES;
            const float* bs = basis + ii * C_DIM;
            float w1 = 0.f, w2 = 0.f;
            #pragma unroll
            for (int bb = 0; bb < B_BASES; ++bb) {
                float a = av[bb];
                w1 += a * bs[bb * 2 * C_DIM + lane];
                w2 += a * bs[bb * 2 * C_DIM + 64 + lane];
            }
            const float* qk = (u < RI2) ? q_att : k_att;
            float s = w1 * qk[lane] + w2 * qk[64 + lane];
            #pragma unroll
            for (int off = 32; off; off >>= 1) s += __shfl_xor(s, off, 64);
            if (lane == 0) ws[((u < RI2) ? OFF_WQ : OFF_WK) + ri] = s;
        } else if (u < 2 * RI2 + 2) {
            int j = u - 2 * RI2;
            const float* er = lin_edge_W + j * C_DIM;
            float s = er[lane] * e_att[lane] + er[64 + lane] * e_att[64 + lane];
            #pragma unroll
            for (int off = 32; off; off >>= 1) s += __shfl_xor(s, off, 64);
            if (lane == 0) ws[OFF_LE + j] = s;
        }
    }
}

// K2: permutation — redundant per-block scan of HBLK + ballot ranks; block 0 writes META
__global__ __launch_bounds__(256) void k_perm(const int* __restrict__ node_type,
                                              float* __restrict__ ws) {
    __shared__ int lh[NB_HIST * 4];
    __shared__ int pre[4], tot[4], basel[4];
    __shared__ int wcnt[4][4];
    int tid = threadIdx.x;
    int lane = tid & 63, wv = tid >> 6;
    const int* hblk = (const int*)(ws + OFF_HBLK);
    for (int i = tid; i < NB_HIST * 4; i += 256) lh[i] = hblk[i];
    __syncthreads();
    if (tid < 4) {
        int run = 0, mypre = 0;
        for (int bb = 0; bb < NB_HIST; ++bb) {
            if (bb == (int)blockIdx.x) mypre = run;
            run += lh[bb * 4 + tid];
        }
        pre[tid] = mypre;
        tot[tid] = run;
    }
    __syncthreads();
    if (tid == 0) {
        int t0 = tot[0], t1 = tot[1], t2 = tot[2];
        int b1 = ((t0 + 63) >> 6) << 6;
        int b2 = b1 + (((t1 + 63) >> 6) << 6);
        int b3 = b2 + (((t2 + 63) >> 6) << 6);
        basel[0] = 0; basel[1] = b1; basel[2] = b2; basel[3] = b3;
        if (blockIdx.x == 0) {
            int* meta = (int*)(ws + OFF_META);
            meta[0] = t0; meta[1] = t1; meta[2] = t2; meta[3] = tot[3];
            meta[4] = 0;  meta[5] = b1; meta[6] = b2; meta[7] = b3;
        }
    }
    __syncthreads();
    int n = blockIdx.x * 256 + tid;
    bool active = n < N_NODES;
    int ty = active ? node_type[n] : -1;
    int myrank = 0;
    #pragma unroll
    for (int t = 0; t < 4; ++t) {
        unsigned long long m = __ballot(ty == t);
        if (lane == 0) wcnt[wv][t] = __popcll(m);
        if (ty == t) myrank = __popcll(m & ((1ULL << lane) - 1ULL));
    }
    __syncthreads();
    if (active) {
        int prew = 0;
        for (int w2 = 0; w2 < wv; ++w2) prew += wcnt[w2][ty];
        int p = basel[ty] + pre[ty] + prew + myrank;
        ((int*)(ws + OFF_PERM))[n] = p;
        ((int*)(ws + OFF_INV))[p] = n;
    }
}

// K3: single-pass bucketed scatter — LDS hist, chunk reservation, record stores
__global__ __launch_bounds__(256) void k_escatter(const float* __restrict__ x,
                                                  const int* __restrict__ edge_index,
                                                  const int* __restrict__ edge_type,
                                                  const float* __restrict__ edge_attr,
                                                  float* __restrict__ ws) {
    __shared__ int hist[NBUCK];
    __shared__ int sbase[NBUCK];
    __shared__ float swq[RI2], swk[RI2], sle[2];
    int tid = threadIdx.x;
    for (int i = tid; i < NBUCK; i += 256) hist[i] = 0;
    if (tid < RI2) { swq[tid] = ws[OFF_WQ + tid]; swk[tid] = ws[OFF_WK + tid]; }
    if (tid < 2) sle[tid] = ws[OFF_LE + tid];
    __syncthreads();

    const int* perm = (const int*)(ws + OFF_PERM);
    int base = blockIdx.x * EPB;
    int   rb[8], rm[8];
    float rex[8], rsx[8], rsy[8];
    #pragma unroll
    for (int k = 0; k < 8; ++k) {
        int e = base + k * 256 + tid;
        rb[k] = -1;
        if (e < N_EDGES) {
            int src = edge_index[e];
            int dst = edge_index[N_EDGES + e];
            int r   = edge_type[e];
            int p   = perm[dst];
            float2 ea = *(const float2*)(edge_attr + 2 * e);
            float2 xs = *(const float2*)(x + 2 * src);
            float2 xd = *(const float2*)(x + 2 * dst);
            float alpha = xd.x * swq[2 * r] + xd.y * swq[2 * r + 1]
                        + xs.x * swk[2 * r] + xs.y * swk[2 * r + 1]
                        + ea.x * sle[0]     + ea.y * sle[1];
            alpha = alpha > 0.f ? alpha : 0.2f * alpha;
            float ex = __expf(alpha);
            rb[k]  = p >> 6;
            rm[k]  = (r << 6) | (p & 63);
            rex[k] = ex;
            rsx[k] = ex * xs.x;
            rsy[k] = ex * xs.y;
            atomicAdd(&hist[rb[k]], 1);
        }
    }
    __syncthreads();
    int* gcur = (int*)(ws + OFF_ECUR);
    for (int i = tid; i < NBUCK; i += 256) {
        int c = hist[i];
        sbase[i] = (c > 0) ? atomicAdd(&gcur[i], c) : 0;
    }
    __syncthreads();
    float4* rec = (float4*)(ws + OFF_EREC);
    #pragma unroll
    for (int k = 0; k < 8; ++k) {
        if (rb[k] >= 0) {
            int slot = atomicAdd(&sbase[rb[k]], 1);
            rec[(size_t)rb[k] * CAP + slot] =
                make_float4(__int_as_float(rm[k]), rex[k], rsx[k], rsy[k]);
        }
    }
}

// K4: fused node pass v3 — full weight residency, monolithic GEMM loops, 8 barriers
__global__ __launch_bounds__(256) void k_node(
        const float* __restrict__ ws, const float* __restrict__ conv_bias,
        const float* __restrict__ lin0_W, const float* __restrict__ lin0_b,
        const float* __restrict__ lin1_W, const float* __restrict__ lin1_b,
        const float* __restrict__ lin2_W, const float* __restrict__ lin2_b,
        const float* __restrict__ fin_W,  const float* __restrict__ fin_b,
        float* __restrict__ out) {
    __shared__ float L[LDS_FLOATS];
    int tid  = threadIdx.x;
    int lane = tid & 63;
    int wv   = tid >> 6;
    int p0   = blockIdx.x * 64;

    const int* meta = (const int*)(ws + OFF_META);
    int b1 = meta[5], b2 = meta[6], b3 = meta[7];
    int t  = (p0 >= b1) + (p0 >= b2) + (p0 >= b3);   // block-uniform
    int bp = meta[4 + t];
    int cnt = meta[t];

    // ---------- phase 0: zero sT+den; stage wT full, W0 full, FW/FB
    for (int i = tid; i < RI2 * 68; i += 256) L[ST + i] = 0.f;
    if (tid < 64) L[SM_DINV + tid] = 0.f;
    if (tid >= 64 && tid < 142) {
        int i = tid - 64;
        if (i < 76) L[SM_FW + i] = fin_W[t * 76 + i];
        else        L[SM_FB + i - 76] = fin_b[t * 2 + i - 76];
    }
    const float* wT_g = ws + OFF_WT;
    for (int i4 = tid; i4 < 2240; i4 += 256) {             // wT: 8960 floats
        float4 v = ((const float4*)wT_g)[i4];
        *(float4*)&L[WT + i4 * 4] = v;
    }
    const float* W0g = lin0_W + t * C_DIM * HL_DIM;
    for (int i = tid; i < C_DIM * HL_DIM; i += 256) {      // W0: [128][38] -> stride 40
        int cc = i / 38, j = i - cc * 38;
        L[W0F + cc * 40 + j] = W0g[i];
    }
    __syncthreads();   // B1

    // ---------- phase 1: accumulate this bucket's edge records (LDS atomics)
    {
        int ecnt = ((const int*)(ws + OFF_ECUR))[blockIdx.x];
        const float4* rec = (const float4*)(ws + OFF_EREC) + (size_t)blockIdx.x * CAP;
        for (int i = tid; i < ecnt; i += 256) {
            float4 v = rec[i];
            int m = __float_as_int(v.x);
            int n = m & 63, r = m >> 6;
            atomicAdd(&L[ST + (2 * r) * 68 + n],     v.z);
            atomicAdd(&L[ST + (2 * r + 1) * 68 + n], v.w);
            atomicAdd(&L[SM_DINV + n],               v.y);
        }
    }
    __syncthreads();   // B2
    if (tid < 64) L[SM_DINV + tid] = 1.0f / (L[SM_DINV + tid] + 1e-16f);

    // ---------- GEMM1: H[64n x 128c] = sT x wT — 70 straight k-iters, no barriers
    int ng = lane & 15, cg_ = lane >> 4;
    int c0 = wv * 32 + cg_ * 8;
    float acc[32];
    #pragma unroll
    for (int i = 0; i < 32; ++i) acc[i] = 0.f;
    #pragma unroll 5
    for (int kk = 0; kk < RI2; ++kk) {
        float4 a4 = *(const float4*)&L[ST + kk * 68 + ng * 4];
        float4 wa = *(const float4*)&L[WT + kk * 128 + c0];
        float4 wc = *(const float4*)&L[WT + kk * 128 + c0 + 4];
        float a_[4] = {a4.x, a4.y, a4.z, a4.w};
        float w_[8] = {wa.x, wa.y, wa.z, wa.w, wc.x, wc.y, wc.z, wc.w};
        #pragma unroll
        for (int ni = 0; ni < 4; ++ni)
            #pragma unroll
            for (int ci = 0; ci < 8; ++ci)
                acc[ni * 8 + ci] += a_[ni] * w_[ci];
    }
    __syncthreads();   // B3: ST+WT reads done; SM_DINV writes visible

    // epilogue 1: h = relu(acc*dinv + cb) -> H[c][n] ; stage W1/W2 into dead WT hole
    {
        float4 dv = *(const float4*)&L[SM_DINV + ng * 4];
        float d_[4] = {dv.x, dv.y, dv.z, dv.w};
        #pragma unroll
        for (int ci = 0; ci < 8; ++ci) {
            float cb = conv_bias[c0 + ci];
            float4 hv;
            float h0 = acc[0 * 8 + ci] * d_[0] + cb;
            float h1 = acc[1 * 8 + ci] * d_[1] + cb;
            float h2 = acc[2 * 8 + ci] * d_[2] + cb;
            float h3 = acc[3 * 8 + ci] * d_[3] + cb;
            hv.x = h0 > 0.f ? h0 : 0.f;
            hv.y = h1 > 0.f ? h1 : 0.f;
            hv.z = h2 > 0.f ? h2 : 0.f;
            hv.w = h3 > 0.f ? h3 : 0.f;
            *(float4*)&L[HH + (c0 + ci) * 64 + ng * 4] = hv;
        }
    }
    {
        const float* W1g = lin1_W + t * HL_DIM * HL_DIM;
        const float* W2g = lin2_W + t * HL_DIM * HL_DIM;
        for (int i = tid; i < HL_DIM * HL_DIM; i += 256) {
            int cc = i / 38, j = i - cc * 38;
            L[W1S + cc * 40 + j] = W1g[i];
            L[W2S + cc * 40 + j] = W2g[i];
        }
    }
    __syncthreads();   // B4: H + W1/W2 ready

    // ---------- GEMM2: y0[64n x 48j] = H x W0 — 128 straight k-iters; waves 0..2
    int jg = lane >> 4;
    int j0 = wv * 16 + jg * 4;
    float acc2[16];
    #pragma unroll
    for (int i = 0; i < 16; ++i) acc2[i] = 0.f;
    if (wv < 3) {
        #pragma unroll 4
        for (int kk = 0; kk < C_DIM; ++kk) {
            float4 a4 = *(const float4*)&L[HH + kk * 64 + ng * 4];
            float4 w4 = *(const float4*)&L[W0F + kk * 40 + j0];
            float a_[4] = {a4.x, a4.y, a4.z, a4.w};
            float w_[4] = {w4.x, w4.y, w4.z, w4.w};
            #pragma unroll
            for (int ni = 0; ni < 4; ++ni)
                #pragma unroll
                for (int ji = 0; ji < 4; ++ji)
                    acc2[ni * 4 + ji] += a_[ni] * w_[ji];
        }
    }
    __syncthreads();   // B5: all H reads done

    // epilogue 2 (waves 0..2): relu(y0 + b0) -> Y0T over dead H rows
    if (wv < 3) {
        #pragma unroll
        for (int ji = 0; ji < 4; ++ji) {
            int j = j0 + ji;
            float b = (j < HL_DIM) ? lin0_b[t * HL_DIM + j] : 0.f;
            float4 yv;
            float y0 = acc2[0 * 4 + ji] + b;
            float y1 = acc2[1 * 4 + ji] + b;
            float y2 = acc2[2 * 4 + ji] + b;
            float y3 = acc2[3 * 4 + ji] + b;
            yv.x = y0 > 0.f ? y0 : 0.f;
            yv.y = y1 > 0.f ? y1 : 0.f;
            yv.z = y2 > 0.f ? y2 : 0.f;
            yv.w = y3 > 0.f ? y3 : 0.f;
            *(float4*)&L[Y0T + j * 68 + ng * 4] = yv;
        }
    }
    __syncthreads();   // B6: Y0T complete

    // ---------- GEMM3: y1 = y0 x W1 (k=38) ; waves 0..2 ; write Y1T (disjoint)
    if (wv < 3) {
        float acc3[16];
        #pragma unroll
        for (int i = 0; i < 16; ++i) acc3[i] = 0.f;
        #pragma unroll 2
        for (int kk = 0; kk < HL_DIM; ++kk) {
            float4 a4 = *(const float4*)&L[Y0T + kk * 68 + ng * 4];
            float4 w4 = *(const float4*)&L[W1S + kk * 40 + j0];
            float a_[4] = {a4.x, a4.y, a4.z, a4.w};
            float w_[4] = {w4.x, w4.y, w4.z, w4.w};
            #pragma unroll
            for (int ni = 0; ni < 4; ++ni)
                #pragma unroll
                for (int ji = 0; ji < 4; ++ji)
                    acc3[ni * 4 + ji] += a_[ni] * w_[ji];
        }
        #pragma unroll
        for (int ji = 0; ji < 4; ++ji) {
            int j = j0 + ji;
            float b = (j < HL_DIM) ? lin1_b[t * HL_DIM + j] : 0.f;
            float4 yv;
            float y0 = acc3[0 * 4 + ji] + b;
            float y1 = acc3[1 * 4 + ji] + b;
            float y2 = acc3[2 * 4 + ji] + b;
            float y3 = acc3[3 * 4 + ji] + b;
            yv.x = y0 > 0.f ? y0 : 0.f;
            yv.y = y1 > 0.f ? y1 : 0.f;
            yv.z = y2 > 0.f ? y2 : 0.f;
            yv.w = y3 > 0.f ? y3 : 0.f;
            *(float4*)&L[Y1T + j * 68 + ng * 4] = yv;
        }
    }
    __syncthreads();   // B7: Y1T complete; Y0T reads done

    // ---------- GEMM4: y2 = y1 x W2 (no relu) ; waves 0..2 ; Y2T over dead Y0T
    if (wv < 3) {
        float acc4[16];
        #pragma unroll
        for (int i = 0; i < 16; ++i) acc4[i] = 0.f;
        #pragma unroll 2
        for (int kk = 0; kk < HL_DIM; ++kk) {
            float4 a4 = *(const float4*)&L[Y1T + kk * 68 + ng * 4];
            float4 w4 = *(const float4*)&L[W2S + kk * 40 + j0];
            float a_[4] = {a4.x, a4.y, a4.z, a4.w};
            float w_[4] = {w4.x, w4.y, w4.z, w4.w};
            #pragma unroll
            for (int ni = 0; ni < 4; ++ni)
                #pragma unroll
                for (int ji = 0; ji < 4; ++ji)
                    acc4[ni * 4 + ji] += a_[ni] * w_[ji];
        }
        #pragma unroll
        for (int ji = 0; ji < 4; ++ji) {
            int j = j0 + ji;
            float b = (j < HL_DIM) ? lin2_b[t * HL_DIM + j] : 0.f;
            float4 yv;
            yv.x = acc4[0 * 4 + ji] + b;
            yv.y = acc4[1 * 4 + ji] + b;
            yv.z = acc4[2 * 4 + ji] + b;
            yv.w = acc4[3 * 4 + ji] + b;
            *(float4*)&L[Y2T + j * 68 + ng * 4] = yv;
        }
    }
    __syncthreads();   // B8: Y2T complete

    // ---------- final: fin [38]->[2], thread-per-node (wave 0)
    if (tid < 64) {
        int p = p0 + tid;
        bool valid = (p - bp) < cnt;
        float o0 = L[SM_FB], o1 = L[SM_FB + 1];
        for (int jj = 0; jj < HL_DIM; ++jj) {
            float v = L[Y2T + jj * 68 + tid];
            float2 f = *(const float2*)&L[SM_FW + jj * 2];
            o0 += v * f.x;
            o1 += v * f.y;
        }
        if (t == 0) o1 = fabsf(o1);
        if (valid) {
            int orig = ((const int*)(ws + OFF_INV))[p];
            ((float2*)out)[orig] = make_float2(o0, o1);
        }
    }
}

extern "C" void kernel_launch(void* const* d_in, const int* in_sizes, int n_in,
                              void* d_out, int out_size, void* d_ws, size_t ws_size,
                              hipStream_t stream) {
    const float* x          = (const float*)d_in[0];
    const int*   edge_index = (const int*)  d_in[1];
    const int*   edge_type  = (const int*)  d_in[2];
    const float* edge_attr  = (const float*)d_in[3];
    const int*   node_type  = (const int*)  d_in[4];
    const float* basis      = (const float*)d_in[5];
    const float* att_rel    = (const float*)d_in[6];
    const float* q_att      = (const float*)d_in[7];
    const float* k_att      = (const float*)d_in[8];
    const float* e_att      = (const float*)d_in[9];
    const float* lin_edge_W = (const float*)d_in[10];
    const float* conv_bias  = (const float*)d_in[11];
    const float* lin0_W     = (const float*)d_in[12];
    const float* lin0_b     = (const float*)d_in[13];
    const float* lin1_W     = (const float*)d_in[14];
    const float* lin1_b     = (const float*)d_in[15];
    const float* lin2_W     = (const float*)d_in[16];
    const float* lin2_b     = (const float*)d_in[17];
    const float* fin_W      = (const float*)d_in[18];
    const float* fin_b      = (const float*)d_in[19];

    float* ws  = (float*)d_ws;
    float* out = (float*)d_out;

    k_init    <<<NB_HIST + 35 + 1 + 36, 256, 0, stream>>>(node_type, basis, att_rel,
                                                          q_att, k_att, e_att, lin_edge_W, ws);
    k_perm    <<<NB_HIST, 256, 0, stream>>>(node_type, ws);
    k_escatter<<<NB_HIST, 256, 0, stream>>>(x, edge_index, edge_type, edge_attr, ws);
    k_node    <<<NBUCK, 256, 0, stream>>>(ws, conv_bias,
                                          lin0_W, lin0_b, lin1_W, lin1_b,
                                          lin2_W, lin2_b, fin_W, fin_b, out);
}